// Round 3
// baseline (691.613 us; speedup 1.0000x reference)
//
#include <hip/hip_runtime.h>

// Static float4 component access (folds to .x/.y/.z/.w after unroll).
#define F4E(v,i) ((i)==0?(v).x:((i)==1?(v).y:((i)==2?(v).z:(v).w)))

#define CHUNK 8192      // edges per partition block (512 threads x 16)

// ---------------------------------------------------------------------------
// Bucket histogram: bucket = dst >> 8 (256 nodes per bucket), NB <= 512.
__global__ __launch_bounds__(512) void k_bhist(
    const int* __restrict__ ei, int* __restrict__ bhist, int E, int NB)
{
    __shared__ int cnt[512];
    int t = threadIdx.x;
    cnt[t] = 0;
    __syncthreads();
    int base = blockIdx.x * CHUNK;
#pragma unroll
    for (int i = 0; i < 16; ++i) {
        int e = base + i * 512 + t;
        if (e < E) {
            int dst = ei[E + e];
            atomicAdd(&cnt[dst >> 8], 1);
        }
    }
    __syncthreads();
    if (t < NB && cnt[t]) atomicAdd(&bhist[t], cnt[t]);
}

// Exclusive scan of bucket counts (NB <= 512), writes bstart + cursor init.
__global__ __launch_bounds__(512) void k_bscan(
    const int* __restrict__ bhist, int* __restrict__ bstart,
    int* __restrict__ gcursor, int NB, int E)
{
    __shared__ int s[512];
    int t = threadIdx.x;
    int v0 = (t < NB) ? bhist[t] : 0;
    s[t] = v0;
    __syncthreads();
    for (int off = 1; off < 512; off <<= 1) {
        int v = (t >= off) ? s[t - off] : 0;
        __syncthreads();
        s[t] += v;
        __syncthreads();
    }
    if (t < NB) { int ex = s[t] - v0; bstart[t] = ex; gcursor[t] = ex; }
    if (t == 0) bstart[NB] = E;
}

// Partition edges into bucket-contiguous packed list, coalesced flush.
// packed = (src << 8) | (dst & 255); requires N < 2^17 (holds: 100000).
__global__ __launch_bounds__(512) void k_partition(
    const int* __restrict__ ei, int* __restrict__ gcursor,
    int* __restrict__ epack, int E)
{
    __shared__ int cnt[512], sc[512], lbase[512], gbase[512], lcnt[512];
    __shared__ int stage[CHUNK];
    __shared__ unsigned short stageb[CHUNK];
    int t = threadIdx.x;
    cnt[t] = 0; lcnt[t] = 0;
    __syncthreads();

    int base = blockIdx.x * CHUNK;
    int pk[16], bb[16];
#pragma unroll
    for (int i = 0; i < 16; ++i) {
        int e = base + i * 512 + t;
        if (e < E) {
            int src = ei[e], dst = ei[E + e];
            pk[i] = (src << 8) | (dst & 255);
            bb[i] = dst >> 8;
            atomicAdd(&cnt[bb[i]], 1);
        } else bb[i] = -1;
    }
    __syncthreads();

    int v0 = cnt[t];
    sc[t] = v0;
    __syncthreads();
    for (int off = 1; off < 512; off <<= 1) {
        int v = (t >= off) ? sc[t - off] : 0;
        __syncthreads();
        sc[t] += v;
        __syncthreads();
    }
    lbase[t] = sc[t] - v0;
    if (v0 > 0) gbase[t] = atomicAdd(&gcursor[t], v0);
    __syncthreads();

#pragma unroll
    for (int i = 0; i < 16; ++i) {
        if (bb[i] >= 0) {
            int loc = atomicAdd(&lcnt[bb[i]], 1);
            int slot = lbase[bb[i]] + loc;
            stage[slot] = pk[i];
            stageb[slot] = (unsigned short)bb[i];
        }
    }
    __syncthreads();

    int m = min(CHUNK, E - base);
#pragma unroll
    for (int i = 0; i < 16; ++i) {
        int slot = i * 512 + t;
        if (slot < m) {
            int b = stageb[slot];
            epack[gbase[b] + (slot - lbase[b])] = stage[slot];
        }
    }
}

// ---------------------------------------------------------------------------
// Fused layer 1: LDS-tile gather of x (F=16) + GraphConv(16->32) + relu.
__global__ __launch_bounds__(256) void k_l1(
    const float* __restrict__ x, const int* __restrict__ bstart,
    const int* __restrict__ epack,
    const float* __restrict__ wroot, const float* __restrict__ wrel,
    const float* __restrict__ bias, float* __restrict__ h1, int N)
{
    __shared__ float tile[256 * 17];                  // stride 17: odd, bank-uniform
    __shared__ float4 s_wr[128], s_wl[128], s_b[8];   // 16x32 weights, bias 32
    int t = threadIdx.x;
    if (t < 128) {
        s_wr[t] = reinterpret_cast<const float4*>(wroot)[t];
        s_wl[t] = reinterpret_cast<const float4*>(wrel)[t];
    }
    if (t < 8) s_b[t] = reinterpret_cast<const float4*>(bias)[t];
    for (int i = t; i < 256 * 17; i += 256) tile[i] = 0.f;
    __syncthreads();

    int b = blockIdx.x;
    int s0 = bstart[b], s1 = bstart[b + 1];
    // 2 edges in flight per thread to hide random-read latency.
    for (int e = s0 + t; e < s1; e += 512) {
        int pk0 = epack[e];
        int e1 = e + 256;
        int pk1 = (e1 < s1) ? epack[e1] : -1;
        {
            int src = ((unsigned)pk0) >> 8, dlo = pk0 & 255;
            const float4* xr = reinterpret_cast<const float4*>(x + (size_t)src * 16);
            float4 v0 = xr[0], v1 = xr[1], v2 = xr[2], v3 = xr[3];
            float* tr = tile + dlo * 17;
            atomicAdd(tr + 0,  v0.x); atomicAdd(tr + 1,  v0.y);
            atomicAdd(tr + 2,  v0.z); atomicAdd(tr + 3,  v0.w);
            atomicAdd(tr + 4,  v1.x); atomicAdd(tr + 5,  v1.y);
            atomicAdd(tr + 6,  v1.z); atomicAdd(tr + 7,  v1.w);
            atomicAdd(tr + 8,  v2.x); atomicAdd(tr + 9,  v2.y);
            atomicAdd(tr + 10, v2.z); atomicAdd(tr + 11, v2.w);
            atomicAdd(tr + 12, v3.x); atomicAdd(tr + 13, v3.y);
            atomicAdd(tr + 14, v3.z); atomicAdd(tr + 15, v3.w);
        }
        if (pk1 >= 0) {
            int src = ((unsigned)pk1) >> 8, dlo = pk1 & 255;
            const float4* xr = reinterpret_cast<const float4*>(x + (size_t)src * 16);
            float4 v0 = xr[0], v1 = xr[1], v2 = xr[2], v3 = xr[3];
            float* tr = tile + dlo * 17;
            atomicAdd(tr + 0,  v0.x); atomicAdd(tr + 1,  v0.y);
            atomicAdd(tr + 2,  v0.z); atomicAdd(tr + 3,  v0.w);
            atomicAdd(tr + 4,  v1.x); atomicAdd(tr + 5,  v1.y);
            atomicAdd(tr + 6,  v1.z); atomicAdd(tr + 7,  v1.w);
            atomicAdd(tr + 8,  v2.x); atomicAdd(tr + 9,  v2.y);
            atomicAdd(tr + 10, v2.z); atomicAdd(tr + 11, v2.w);
            atomicAdd(tr + 12, v3.x); atomicAdd(tr + 13, v3.y);
            atomicAdd(tr + 14, v3.z); atomicAdd(tr + 15, v3.w);
        }
    }
    __syncthreads();

    int n = (b << 8) + t;
    if (n >= N) return;
    const float4* xr = reinterpret_cast<const float4*>(x + (size_t)n * 16);
    const float* tr = tile + t * 17;

    float4 acc[8];
#pragma unroll
    for (int jc = 0; jc < 8; ++jc) acc[jc] = s_b[jc];

#pragma unroll
    for (int kc = 0; kc < 4; ++kc) {
        float4 a4 = xr[kc];
#pragma unroll
        for (int kk = 0; kk < 4; ++kk) {
            float a = F4E(a4, kk);
            int k = kc * 4 + kk;
            float g = tr[k];
#pragma unroll
            for (int jc = 0; jc < 8; ++jc) {
                float4 wr = s_wr[k * 8 + jc];
                float4 wl = s_wl[k * 8 + jc];
                acc[jc].x += a * wr.x + g * wl.x;
                acc[jc].y += a * wr.y + g * wl.y;
                acc[jc].z += a * wr.z + g * wl.z;
                acc[jc].w += a * wr.w + g * wl.w;
            }
        }
    }

    float4* o = reinterpret_cast<float4*>(h1 + (size_t)n * 32);
#pragma unroll
    for (int jc = 0; jc < 8; ++jc) {
        float4 v = acc[jc];
        v.x = fmaxf(v.x, 0.f); v.y = fmaxf(v.y, 0.f);
        v.z = fmaxf(v.z, 0.f); v.w = fmaxf(v.w, 0.f);
        o[jc] = v;
    }
}

// ---------------------------------------------------------------------------
// Fused layer 2 + FC head: LDS-tile gather of h1 (F=32) + GraphConv(32->64)
// + relu + fc1(64->32) + relu + fc2(32->16). Writes final output.
__global__ __launch_bounds__(256) void k_l2(
    const float* __restrict__ h1, const int* __restrict__ bstart,
    const int* __restrict__ epack,
    const float* __restrict__ wroot, const float* __restrict__ wrel,
    const float* __restrict__ bias,
    const float* __restrict__ f1w, const float* __restrict__ f1b,
    const float* __restrict__ f2w, const float* __restrict__ f2b,
    float* __restrict__ out, int N)
{
    __shared__ float tile[256 * 33];                  // 33.0 KB, stride 33
    __shared__ float4 s_wr[512], s_wl[512], s_b[16];  // 32x64 weights, bias 64
    __shared__ float4 s_f1[512], s_f2[128], s_b1[8], s_b2[4];
    int t = threadIdx.x;
    for (int i = t; i < 512; i += 256) {
        s_wr[i] = reinterpret_cast<const float4*>(wroot)[i];
        s_wl[i] = reinterpret_cast<const float4*>(wrel)[i];
        s_f1[i] = reinterpret_cast<const float4*>(f1w)[i];
    }
    if (t < 128) s_f2[t] = reinterpret_cast<const float4*>(f2w)[t];
    if (t < 16) s_b[t]  = reinterpret_cast<const float4*>(bias)[t];
    if (t < 8)  s_b1[t] = reinterpret_cast<const float4*>(f1b)[t];
    if (t < 4)  s_b2[t] = reinterpret_cast<const float4*>(f2b)[t];
    for (int i = t; i < 256 * 33; i += 256) tile[i] = 0.f;
    __syncthreads();

    int b = blockIdx.x;
    int s0 = bstart[b], s1 = bstart[b + 1];
    for (int e = s0 + t; e < s1; e += 512) {
        int pk0 = epack[e];
        int e1 = e + 256;
        int pk1 = (e1 < s1) ? epack[e1] : -1;
        {
            int src = ((unsigned)pk0) >> 8, dlo = pk0 & 255;
            const float4* xr = reinterpret_cast<const float4*>(h1 + (size_t)src * 32);
            float* tr = tile + dlo * 33;
#pragma unroll
            for (int c = 0; c < 8; ++c) {
                float4 v = xr[c];
                atomicAdd(tr + c * 4 + 0, v.x); atomicAdd(tr + c * 4 + 1, v.y);
                atomicAdd(tr + c * 4 + 2, v.z); atomicAdd(tr + c * 4 + 3, v.w);
            }
        }
        if (pk1 >= 0) {
            int src = ((unsigned)pk1) >> 8, dlo = pk1 & 255;
            const float4* xr = reinterpret_cast<const float4*>(h1 + (size_t)src * 32);
            float* tr = tile + dlo * 33;
#pragma unroll
            for (int c = 0; c < 8; ++c) {
                float4 v = xr[c];
                atomicAdd(tr + c * 4 + 0, v.x); atomicAdd(tr + c * 4 + 1, v.y);
                atomicAdd(tr + c * 4 + 2, v.z); atomicAdd(tr + c * 4 + 3, v.w);
            }
        }
    }
    __syncthreads();

    int n = (b << 8) + t;
    if (n >= N) return;
    const float4* xr = reinterpret_cast<const float4*>(h1 + (size_t)n * 32);
    const float* tr = tile + t * 33;

    // GraphConv layer 2 -> h2 (64) in registers.
    float4 acc[16];
#pragma unroll
    for (int jc = 0; jc < 16; ++jc) acc[jc] = s_b[jc];

#pragma unroll
    for (int kc = 0; kc < 8; ++kc) {
        float4 a4 = xr[kc];
#pragma unroll
        for (int kk = 0; kk < 4; ++kk) {
            float a = F4E(a4, kk);
            int k = kc * 4 + kk;
            float g = tr[k];
#pragma unroll
            for (int jc = 0; jc < 16; ++jc) {
                float4 wr = s_wr[k * 16 + jc];
                float4 wl = s_wl[k * 16 + jc];
                acc[jc].x += a * wr.x + g * wl.x;
                acc[jc].y += a * wr.y + g * wl.y;
                acc[jc].z += a * wr.z + g * wl.z;
                acc[jc].w += a * wr.w + g * wl.w;
            }
        }
    }
#pragma unroll
    for (int jc = 0; jc < 16; ++jc) {
        acc[jc].x = fmaxf(acc[jc].x, 0.f); acc[jc].y = fmaxf(acc[jc].y, 0.f);
        acc[jc].z = fmaxf(acc[jc].z, 0.f); acc[jc].w = fmaxf(acc[jc].w, 0.f);
    }

    // fc1 (64->32) + relu
    float4 acc3[8];
#pragma unroll
    for (int jc = 0; jc < 8; ++jc) acc3[jc] = s_b1[jc];
#pragma unroll
    for (int k = 0; k < 64; ++k) {
        float a = F4E(acc[k >> 2], k & 3);
#pragma unroll
        for (int jc = 0; jc < 8; ++jc) {
            float4 w = s_f1[k * 8 + jc];
            acc3[jc].x += a * w.x; acc3[jc].y += a * w.y;
            acc3[jc].z += a * w.z; acc3[jc].w += a * w.w;
        }
    }
#pragma unroll
    for (int jc = 0; jc < 8; ++jc) {
        acc3[jc].x = fmaxf(acc3[jc].x, 0.f); acc3[jc].y = fmaxf(acc3[jc].y, 0.f);
        acc3[jc].z = fmaxf(acc3[jc].z, 0.f); acc3[jc].w = fmaxf(acc3[jc].w, 0.f);
    }

    // fc2 (32->16)
    float4 acc4[4];
#pragma unroll
    for (int jc = 0; jc < 4; ++jc) acc4[jc] = s_b2[jc];
#pragma unroll
    for (int k = 0; k < 32; ++k) {
        float a = F4E(acc3[k >> 2], k & 3);
#pragma unroll
        for (int jc = 0; jc < 4; ++jc) {
            float4 w = s_f2[k * 4 + jc];
            acc4[jc].x += a * w.x; acc4[jc].y += a * w.y;
            acc4[jc].z += a * w.z; acc4[jc].w += a * w.w;
        }
    }

    float4* o = reinterpret_cast<float4*>(out + (size_t)n * 16);
#pragma unroll
    for (int jc = 0; jc < 4; ++jc) o[jc] = acc4[jc];
}

// ---------------------------------------------------------------------------
extern "C" void kernel_launch(void* const* d_in, const int* in_sizes, int n_in,
                              void* d_out, int out_size, void* d_ws, size_t ws_size,
                              hipStream_t stream)
{
    const float* x   = (const float*)d_in[0];
    const int*   ei  = (const int*)d_in[1];
    const float* wr1 = (const float*)d_in[2];
    const float* wl1 = (const float*)d_in[3];
    const float* b1  = (const float*)d_in[4];
    const float* wr2 = (const float*)d_in[5];
    const float* wl2 = (const float*)d_in[6];
    const float* b2  = (const float*)d_in[7];
    const float* f1w = (const float*)d_in[8];
    const float* f1b = (const float*)d_in[9];
    const float* f2w = (const float*)d_in[10];
    const float* f2b = (const float*)d_in[11];
    float* out = (float*)d_out;

    const int N  = in_sizes[0] / 16;
    const int E  = in_sizes[1] / 2;
    const int NB = (N + 255) >> 8;      // 256 nodes per bucket, NB <= 512

    // Workspace layout (~19.2 MB of the proven >=51.2 MB):
    //   epack  : E ints
    //   h1     : N*32 floats
    //   bhist  : NB ints, bstart : NB+1 ints, gcursor : NB ints
    int*   epack = (int*)d_ws;
    float* h1    = (float*)d_ws + E;
    int*   bhist   = (int*)((float*)d_ws + E + (size_t)N * 32);
    int*   bstart  = bhist + NB;
    int*   gcursor = bstart + NB + 1;

    hipMemsetAsync(bhist, 0, (size_t)NB * sizeof(int), stream);

    int nchunk = (E + CHUNK - 1) / CHUNK;
    k_bhist    <<<nchunk, 512, 0, stream>>>(ei, bhist, E, NB);
    k_bscan    <<<1,      512, 0, stream>>>(bhist, bstart, gcursor, NB, E);
    k_partition<<<nchunk, 512, 0, stream>>>(ei, gcursor, epack, E);
    k_l1<<<NB, 256, 0, stream>>>(x, bstart, epack, wr1, wl1, b1, h1, N);
    k_l2<<<NB, 256, 0, stream>>>(h1, bstart, epack, wr2, wl2, b2,
                                 f1w, f1b, f2w, f2b, out, N);
}

// Round 4
// 251.590 us; speedup vs baseline: 2.7490x; 2.7490x over previous
//
#include <hip/hip_runtime.h>

// Static float4 component access (folds to .x/.y/.z/.w after unroll).
#define F4E(v,i) ((i)==0?(v).x:((i)==1?(v).y:((i)==2?(v).z:(v).w)))

#define CHUNK 8192      // edges per partition block (512 threads x 16)

// ---------------------------------------------------------------------------
// Bucket histogram: bucket = dst >> 8 (256 nodes per bucket), NB <= 512.
__global__ __launch_bounds__(512) void k_bhist(
    const int* __restrict__ ei, int* __restrict__ bhist, int E, int NB)
{
    __shared__ int cnt[512];
    int t = threadIdx.x;
    cnt[t] = 0;
    __syncthreads();
    int base = blockIdx.x * CHUNK;
#pragma unroll
    for (int i = 0; i < 16; ++i) {
        int e = base + i * 512 + t;
        if (e < E) {
            int dst = ei[E + e];
            atomicAdd(&cnt[dst >> 8], 1);
        }
    }
    __syncthreads();
    if (t < NB && cnt[t]) atomicAdd(&bhist[t], cnt[t]);
}

// Exclusive scan of bucket counts (NB <= 512), writes bstart + cursor init.
__global__ __launch_bounds__(512) void k_bscan(
    const int* __restrict__ bhist, int* __restrict__ bstart,
    int* __restrict__ gcursor, int NB, int E)
{
    __shared__ int s[512];
    int t = threadIdx.x;
    int v0 = (t < NB) ? bhist[t] : 0;
    s[t] = v0;
    __syncthreads();
    for (int off = 1; off < 512; off <<= 1) {
        int v = (t >= off) ? s[t - off] : 0;
        __syncthreads();
        s[t] += v;
        __syncthreads();
    }
    if (t < NB) { int ex = s[t] - v0; bstart[t] = ex; gcursor[t] = ex; }
    if (t == 0) bstart[NB] = E;
}

// Partition edges into bucket-contiguous packed list, coalesced flush.
// packed = (src << 8) | (dst & 255); requires N < 2^17 (holds: 100000).
__global__ __launch_bounds__(512) void k_partition(
    const int* __restrict__ ei, int* __restrict__ gcursor,
    int* __restrict__ epack, int E)
{
    __shared__ int cnt[512], sc[512], lbase[512], gbase[512], lcnt[512];
    __shared__ int stage[CHUNK];
    __shared__ unsigned short stageb[CHUNK];
    int t = threadIdx.x;
    cnt[t] = 0; lcnt[t] = 0;
    __syncthreads();

    int base = blockIdx.x * CHUNK;
    int pk[16], bb[16];
#pragma unroll
    for (int i = 0; i < 16; ++i) {
        int e = base + i * 512 + t;
        if (e < E) {
            int src = ei[e], dst = ei[E + e];
            pk[i] = (src << 8) | (dst & 255);
            bb[i] = dst >> 8;
            atomicAdd(&cnt[bb[i]], 1);
        } else bb[i] = -1;
    }
    __syncthreads();

    int v0 = cnt[t];
    sc[t] = v0;
    __syncthreads();
    for (int off = 1; off < 512; off <<= 1) {
        int v = (t >= off) ? sc[t - off] : 0;
        __syncthreads();
        sc[t] += v;
        __syncthreads();
    }
    lbase[t] = sc[t] - v0;
    if (v0 > 0) gbase[t] = atomicAdd(&gcursor[t], v0);
    __syncthreads();

#pragma unroll
    for (int i = 0; i < 16; ++i) {
        if (bb[i] >= 0) {
            int loc = atomicAdd(&lcnt[bb[i]], 1);
            int slot = lbase[bb[i]] + loc;
            stage[slot] = pk[i];
            stageb[slot] = (unsigned short)bb[i];
        }
    }
    __syncthreads();

    int m = min(CHUNK, E - base);
#pragma unroll
    for (int i = 0; i < 16; ++i) {
        int slot = i * 512 + t;
        if (slot < m) {
            int b = stageb[slot];
            epack[gbase[b] + (slot - lbase[b])] = stage[slot];
        }
    }
}

// ---------------------------------------------------------------------------
// Per-bucket counting sort by dst&255 -> per-node CSR (rs + esorted of src).
// Scatter writes confined to a 16KB window per block -> no write amp.
__global__ __launch_bounds__(256) void k_sort(
    const int* __restrict__ bstart, const int* __restrict__ epack,
    int* __restrict__ rs, int* __restrict__ esorted, int N, int E)
{
    __shared__ int hist[256], cur[256], sc[256];
    int t = threadIdx.x;
    int b = blockIdx.x;
    int s0 = bstart[b], s1 = bstart[b + 1];
    hist[t] = 0;
    __syncthreads();
    for (int e = s0 + t; e < s1; e += 256)
        atomicAdd(&hist[epack[e] & 255], 1);
    __syncthreads();

    int v0 = hist[t];
    sc[t] = v0;
    __syncthreads();
    for (int off = 1; off < 256; off <<= 1) {
        int v = (t >= off) ? sc[t - off] : 0;
        __syncthreads();
        sc[t] += v;
        __syncthreads();
    }
    int excl = sc[t] - v0;
    cur[t] = excl;
    int node = (b << 8) + t;
    if (node < N) rs[node] = s0 + excl;
    if (b == 0 && t == 0) rs[N] = E;
    __syncthreads();

    for (int e = s0 + t; e < s1; e += 256) {
        int pk = epack[e];
        int dlo = pk & 255;
        int pos = s0 + atomicAdd(&cur[dlo], 1);
        esorted[pos] = ((unsigned)pk) >> 8;
    }
}

// ---------------------------------------------------------------------------
// Gather-sum, F=16: 4 threads per node, each owns a float4 of the row.
__global__ __launch_bounds__(256) void k_gather16(
    const float* __restrict__ x, const int* __restrict__ rs,
    const int* __restrict__ esrc, float* __restrict__ agg, int N)
{
    int tid = blockIdx.x * 256 + threadIdx.x;
    int n = tid >> 2, p = tid & 3;
    if (n >= N) return;
    int s0 = rs[n], s1 = rs[n + 1];
    float4 acc = make_float4(0.f, 0.f, 0.f, 0.f);
    int e = s0;
    for (; e + 1 < s1; e += 2) {
        int src0 = esrc[e], src1 = esrc[e + 1];
        float4 v0 = *reinterpret_cast<const float4*>(x + (size_t)src0 * 16 + p * 4);
        float4 v1 = *reinterpret_cast<const float4*>(x + (size_t)src1 * 16 + p * 4);
        acc.x += v0.x + v1.x; acc.y += v0.y + v1.y;
        acc.z += v0.z + v1.z; acc.w += v0.w + v1.w;
    }
    if (e < s1) {
        int src0 = esrc[e];
        float4 v0 = *reinterpret_cast<const float4*>(x + (size_t)src0 * 16 + p * 4);
        acc.x += v0.x; acc.y += v0.y; acc.z += v0.z; acc.w += v0.w;
    }
    *reinterpret_cast<float4*>(agg + (size_t)n * 16 + p * 4) = acc;
}

// Gather-sum, F=32: 8 threads per node.
__global__ __launch_bounds__(256) void k_gather32(
    const float* __restrict__ x, const int* __restrict__ rs,
    const int* __restrict__ esrc, float* __restrict__ agg, int N)
{
    int tid = blockIdx.x * 256 + threadIdx.x;
    int n = tid >> 3, p = tid & 7;
    if (n >= N) return;
    int s0 = rs[n], s1 = rs[n + 1];
    float4 acc = make_float4(0.f, 0.f, 0.f, 0.f);
    int e = s0;
    for (; e + 1 < s1; e += 2) {
        int src0 = esrc[e], src1 = esrc[e + 1];
        float4 v0 = *reinterpret_cast<const float4*>(x + (size_t)src0 * 32 + p * 4);
        float4 v1 = *reinterpret_cast<const float4*>(x + (size_t)src1 * 32 + p * 4);
        acc.x += v0.x + v1.x; acc.y += v0.y + v1.y;
        acc.z += v0.z + v1.z; acc.w += v0.w + v1.w;
    }
    if (e < s1) {
        int src0 = esrc[e];
        float4 v0 = *reinterpret_cast<const float4*>(x + (size_t)src0 * 32 + p * 4);
        acc.x += v0.x; acc.y += v0.y; acc.z += v0.z; acc.w += v0.w;
    }
    *reinterpret_cast<float4*>(agg + (size_t)n * 32 + p * 4) = acc;
}

// ---------------------------------------------------------------------------
// Layer 1: h1[n] = relu(agg[n] @ w_rel(16x32) + b + x[n] @ w_root(16x32))
__global__ __launch_bounds__(256) void k_l1(
    const float* __restrict__ x, const float* __restrict__ agg,
    const float* __restrict__ wroot, const float* __restrict__ wrel,
    const float* __restrict__ bias, float* __restrict__ h1, int N)
{
    __shared__ float4 s_wr[128], s_wl[128], s_b[8];   // 16x32 each, bias 32
    int t = threadIdx.x;
    if (t < 128) {
        s_wr[t] = reinterpret_cast<const float4*>(wroot)[t];
        s_wl[t] = reinterpret_cast<const float4*>(wrel)[t];
    }
    if (t < 8) s_b[t] = reinterpret_cast<const float4*>(bias)[t];
    __syncthreads();

    int n = blockIdx.x * 256 + t;
    if (n >= N) return;
    const float4* xr = reinterpret_cast<const float4*>(x + (size_t)n * 16);
    const float4* ar = reinterpret_cast<const float4*>(agg + (size_t)n * 16);

    float4 acc[8];
#pragma unroll
    for (int jc = 0; jc < 8; ++jc) acc[jc] = s_b[jc];

#pragma unroll
    for (int kc = 0; kc < 4; ++kc) {
        float4 a4 = xr[kc];
        float4 g4 = ar[kc];
#pragma unroll
        for (int kk = 0; kk < 4; ++kk) {
            float a = F4E(a4, kk), g = F4E(g4, kk);
            int k = kc * 4 + kk;
#pragma unroll
            for (int jc = 0; jc < 8; ++jc) {
                float4 wr = s_wr[k * 8 + jc];
                float4 wl = s_wl[k * 8 + jc];
                acc[jc].x += a * wr.x + g * wl.x;
                acc[jc].y += a * wr.y + g * wl.y;
                acc[jc].z += a * wr.z + g * wl.z;
                acc[jc].w += a * wr.w + g * wl.w;
            }
        }
    }

    float4* o = reinterpret_cast<float4*>(h1 + (size_t)n * 32);
#pragma unroll
    for (int jc = 0; jc < 8; ++jc) {
        float4 v = acc[jc];
        v.x = fmaxf(v.x, 0.f); v.y = fmaxf(v.y, 0.f);
        v.z = fmaxf(v.z, 0.f); v.w = fmaxf(v.w, 0.f);
        o[jc] = v;
    }
}

// ---------------------------------------------------------------------------
// Fused layer 2 + FC head: GraphConv(32->64) + relu + fc1 + relu + fc2.
// h2 never leaves registers; writes final output directly.
__global__ __launch_bounds__(256) void k_l2f(
    const float* __restrict__ h1, const float* __restrict__ agg,
    const float* __restrict__ wroot, const float* __restrict__ wrel,
    const float* __restrict__ bias,
    const float* __restrict__ f1w, const float* __restrict__ f1b,
    const float* __restrict__ f2w, const float* __restrict__ f2b,
    float* __restrict__ out, int N)
{
    __shared__ float4 s_wr[512], s_wl[512], s_b[16];  // 32x64 weights, bias 64
    __shared__ float4 s_f1[512], s_f2[128], s_b1[8], s_b2[4];
    int t = threadIdx.x;
    for (int i = t; i < 512; i += 256) {
        s_wr[i] = reinterpret_cast<const float4*>(wroot)[i];
        s_wl[i] = reinterpret_cast<const float4*>(wrel)[i];
        s_f1[i] = reinterpret_cast<const float4*>(f1w)[i];
    }
    if (t < 128) s_f2[t] = reinterpret_cast<const float4*>(f2w)[t];
    if (t < 16) s_b[t]  = reinterpret_cast<const float4*>(bias)[t];
    if (t < 8)  s_b1[t] = reinterpret_cast<const float4*>(f1b)[t];
    if (t < 4)  s_b2[t] = reinterpret_cast<const float4*>(f2b)[t];
    __syncthreads();

    int n = blockIdx.x * 256 + t;
    if (n >= N) return;
    const float4* xr = reinterpret_cast<const float4*>(h1 + (size_t)n * 32);
    const float4* ar = reinterpret_cast<const float4*>(agg + (size_t)n * 32);

    // GraphConv layer 2 -> h2 (64) in registers.
    float4 acc[16];
#pragma unroll
    for (int jc = 0; jc < 16; ++jc) acc[jc] = s_b[jc];

#pragma unroll
    for (int kc = 0; kc < 8; ++kc) {
        float4 a4 = xr[kc];
        float4 g4 = ar[kc];
#pragma unroll
        for (int kk = 0; kk < 4; ++kk) {
            float a = F4E(a4, kk), g = F4E(g4, kk);
            int k = kc * 4 + kk;
#pragma unroll
            for (int jc = 0; jc < 16; ++jc) {
                float4 wr = s_wr[k * 16 + jc];
                float4 wl = s_wl[k * 16 + jc];
                acc[jc].x += a * wr.x + g * wl.x;
                acc[jc].y += a * wr.y + g * wl.y;
                acc[jc].z += a * wr.z + g * wl.z;
                acc[jc].w += a * wr.w + g * wl.w;
            }
        }
    }
#pragma unroll
    for (int jc = 0; jc < 16; ++jc) {
        acc[jc].x = fmaxf(acc[jc].x, 0.f); acc[jc].y = fmaxf(acc[jc].y, 0.f);
        acc[jc].z = fmaxf(acc[jc].z, 0.f); acc[jc].w = fmaxf(acc[jc].w, 0.f);
    }

    // fc1 (64->32) + relu
    float4 acc3[8];
#pragma unroll
    for (int jc = 0; jc < 8; ++jc) acc3[jc] = s_b1[jc];
#pragma unroll
    for (int k = 0; k < 64; ++k) {
        float a = F4E(acc[k >> 2], k & 3);
#pragma unroll
        for (int jc = 0; jc < 8; ++jc) {
            float4 w = s_f1[k * 8 + jc];
            acc3[jc].x += a * w.x; acc3[jc].y += a * w.y;
            acc3[jc].z += a * w.z; acc3[jc].w += a * w.w;
        }
    }
#pragma unroll
    for (int jc = 0; jc < 8; ++jc) {
        acc3[jc].x = fmaxf(acc3[jc].x, 0.f); acc3[jc].y = fmaxf(acc3[jc].y, 0.f);
        acc3[jc].z = fmaxf(acc3[jc].z, 0.f); acc3[jc].w = fmaxf(acc3[jc].w, 0.f);
    }

    // fc2 (32->16)
    float4 acc4[4];
#pragma unroll
    for (int jc = 0; jc < 4; ++jc) acc4[jc] = s_b2[jc];
#pragma unroll
    for (int k = 0; k < 32; ++k) {
        float a = F4E(acc3[k >> 2], k & 3);
#pragma unroll
        for (int jc = 0; jc < 4; ++jc) {
            float4 w = s_f2[k * 4 + jc];
            acc4[jc].x += a * w.x; acc4[jc].y += a * w.y;
            acc4[jc].z += a * w.z; acc4[jc].w += a * w.w;
        }
    }

    float4* o = reinterpret_cast<float4*>(out + (size_t)n * 16);
#pragma unroll
    for (int jc = 0; jc < 4; ++jc) o[jc] = acc4[jc];
}

// ---------------------------------------------------------------------------
extern "C" void kernel_launch(void* const* d_in, const int* in_sizes, int n_in,
                              void* d_out, int out_size, void* d_ws, size_t ws_size,
                              hipStream_t stream)
{
    const float* x   = (const float*)d_in[0];
    const int*   ei  = (const int*)d_in[1];
    const float* wr1 = (const float*)d_in[2];
    const float* wl1 = (const float*)d_in[3];
    const float* b1  = (const float*)d_in[4];
    const float* wr2 = (const float*)d_in[5];
    const float* wl2 = (const float*)d_in[6];
    const float* b2  = (const float*)d_in[7];
    const float* f1w = (const float*)d_in[8];
    const float* f1b = (const float*)d_in[9];
    const float* f2w = (const float*)d_in[10];
    const float* f2b = (const float*)d_in[11];
    float* out = (float*)d_out;

    const int N  = in_sizes[0] / 16;
    const int E  = in_sizes[1] / 2;
    const int NB = (N + 255) >> 8;      // 256 nodes per bucket, NB <= 512

    // Workspace layout (floats/ints, no aliasing; ~45.3MB of >=51.2MB):
    //   h1      : ws[0,            N*32)        12.8 MB
    //   agg2    : ws[N*32,         N*64)        12.8 MB
    //   esorted : E ints                         6.4 MB
    //   epack   : E ints                         6.4 MB
    //   agg1    : N*16 floats                    6.4 MB
    //   rs      : N+1 ints, bhist/bstart/gcursor tiny
    float* ws      = (float*)d_ws;
    float* h1      = ws;
    float* agg2    = ws + (size_t)N * 32;
    int*   esorted = (int*)(ws + (size_t)N * 64);
    int*   epack   = esorted + E;
    float* agg1    = ws + (size_t)N * 64 + (size_t)2 * E;
    int*   rs      = (int*)(agg1 + (size_t)N * 16);
    int*   bhist   = rs + N + 1;
    int*   bstart  = bhist + NB;
    int*   gcursor = bstart + NB + 1;

    hipMemsetAsync(bhist, 0, (size_t)NB * sizeof(int), stream);

    int nchunk = (E + CHUNK - 1) / CHUNK;
    int g_n  = (N + 255) / 256;
    int g_g1 = (N * 4 + 255) / 256;
    int g_g2 = (N * 8 + 255) / 256;

    k_bhist    <<<nchunk, 512, 0, stream>>>(ei, bhist, E, NB);
    k_bscan    <<<1,      512, 0, stream>>>(bhist, bstart, gcursor, NB, E);
    k_partition<<<nchunk, 512, 0, stream>>>(ei, gcursor, epack, E);
    k_sort     <<<NB,     256, 0, stream>>>(bstart, epack, rs, esorted, N, E);

    k_gather16<<<g_g1, 256, 0, stream>>>(x, rs, esorted, agg1, N);
    k_l1      <<<g_n,  256, 0, stream>>>(x, agg1, wr1, wl1, b1, h1, N);
    k_gather32<<<g_g2, 256, 0, stream>>>(h1, rs, esorted, agg2, N);
    k_l2f     <<<g_n,  256, 0, stream>>>(h1, agg2, wr2, wl2, b2,
                                         f1w, f1b, f2w, f2b, out, N);
}

// Round 5
// 232.154 us; speedup vs baseline: 2.9791x; 1.0837x over previous
//
#include <hip/hip_runtime.h>

// Static float4 component access (folds to .x/.y/.z/.w after unroll).
#define F4E(v,i) ((i)==0?(v).x:((i)==1?(v).y:((i)==2?(v).z:(v).w)))

#define CHUNK 8192      // edges per partition block (512 threads x 16)

__device__ inline float4 shfl4b(float4 v, int src) {
    // broadcast from lane `src` within each 4-lane group
    float4 r;
    r.x = __shfl(v.x, src, 4); r.y = __shfl(v.y, src, 4);
    r.z = __shfl(v.z, src, 4); r.w = __shfl(v.w, src, 4);
    return r;
}

// ---------------------------------------------------------------------------
// Bucket histogram: bucket = dst >> 8 (256 nodes per bucket), NB <= 512.
__global__ __launch_bounds__(512) void k_bhist(
    const int* __restrict__ ei, int* __restrict__ bhist, int E, int NB)
{
    __shared__ int cnt[512];
    int t = threadIdx.x;
    cnt[t] = 0;
    __syncthreads();
    int base = blockIdx.x * CHUNK;
#pragma unroll
    for (int i = 0; i < 16; ++i) {
        int e = base + i * 512 + t;
        if (e < E) {
            int dst = ei[E + e];
            atomicAdd(&cnt[dst >> 8], 1);
        }
    }
    __syncthreads();
    if (t < NB && cnt[t]) atomicAdd(&bhist[t], cnt[t]);
}

// Exclusive scan of bucket counts (NB <= 512), writes bstart + cursor init.
__global__ __launch_bounds__(512) void k_bscan(
    const int* __restrict__ bhist, int* __restrict__ bstart,
    int* __restrict__ gcursor, int NB, int E)
{
    __shared__ int s[512];
    int t = threadIdx.x;
    int v0 = (t < NB) ? bhist[t] : 0;
    s[t] = v0;
    __syncthreads();
    for (int off = 1; off < 512; off <<= 1) {
        int v = (t >= off) ? s[t - off] : 0;
        __syncthreads();
        s[t] += v;
        __syncthreads();
    }
    if (t < NB) { int ex = s[t] - v0; bstart[t] = ex; gcursor[t] = ex; }
    if (t == 0) bstart[NB] = E;
}

// Partition edges into bucket-contiguous packed list, coalesced flush.
// packed = (src << 8) | (dst & 255); requires N < 2^17 (holds: 100000).
__global__ __launch_bounds__(512) void k_partition(
    const int* __restrict__ ei, int* __restrict__ gcursor,
    int* __restrict__ epack, int E)
{
    __shared__ int cnt[512], sc[512], lbase[512], gbase[512], lcnt[512];
    __shared__ int stage[CHUNK];
    __shared__ unsigned short stageb[CHUNK];
    int t = threadIdx.x;
    cnt[t] = 0; lcnt[t] = 0;
    __syncthreads();

    int base = blockIdx.x * CHUNK;
    int pk[16], bb[16];
#pragma unroll
    for (int i = 0; i < 16; ++i) {
        int e = base + i * 512 + t;
        if (e < E) {
            int src = ei[e], dst = ei[E + e];
            pk[i] = (src << 8) | (dst & 255);
            bb[i] = dst >> 8;
            atomicAdd(&cnt[bb[i]], 1);
        } else bb[i] = -1;
    }
    __syncthreads();

    int v0 = cnt[t];
    sc[t] = v0;
    __syncthreads();
    for (int off = 1; off < 512; off <<= 1) {
        int v = (t >= off) ? sc[t - off] : 0;
        __syncthreads();
        sc[t] += v;
        __syncthreads();
    }
    lbase[t] = sc[t] - v0;
    if (v0 > 0) gbase[t] = atomicAdd(&gcursor[t], v0);
    __syncthreads();

#pragma unroll
    for (int i = 0; i < 16; ++i) {
        if (bb[i] >= 0) {
            int loc = atomicAdd(&lcnt[bb[i]], 1);
            int slot = lbase[bb[i]] + loc;
            stage[slot] = pk[i];
            stageb[slot] = (unsigned short)bb[i];
        }
    }
    __syncthreads();

    int m = min(CHUNK, E - base);
#pragma unroll
    for (int i = 0; i < 16; ++i) {
        int slot = i * 512 + t;
        if (slot < m) {
            int b = stageb[slot];
            epack[gbase[b] + (slot - lbase[b])] = stage[slot];
        }
    }
}

// ---------------------------------------------------------------------------
// Per-bucket counting sort by dst&255 -> per-node CSR (rs + esorted of src).
__global__ __launch_bounds__(256) void k_sort(
    const int* __restrict__ bstart, const int* __restrict__ epack,
    int* __restrict__ rs, int* __restrict__ esorted, int N, int E)
{
    __shared__ int hist[256], cur[256], sc[256];
    int t = threadIdx.x;
    int b = blockIdx.x;
    int s0 = bstart[b], s1 = bstart[b + 1];
    hist[t] = 0;
    __syncthreads();
    for (int e = s0 + t; e < s1; e += 256)
        atomicAdd(&hist[epack[e] & 255], 1);
    __syncthreads();

    int v0 = hist[t];
    sc[t] = v0;
    __syncthreads();
    for (int off = 1; off < 256; off <<= 1) {
        int v = (t >= off) ? sc[t - off] : 0;
        __syncthreads();
        sc[t] += v;
        __syncthreads();
    }
    int excl = sc[t] - v0;
    cur[t] = excl;
    int node = (b << 8) + t;
    if (node < N) rs[node] = s0 + excl;
    if (b == 0 && t == 0) rs[N] = E;
    __syncthreads();

    for (int e = s0 + t; e < s1; e += 256) {
        int pk = epack[e];
        int dlo = pk & 255;
        int pos = s0 + atomicAdd(&cur[dlo], 1);
        esorted[pos] = ((unsigned)pk) >> 8;
    }
}

// ---------------------------------------------------------------------------
// Fused gather(F=16) + layer1: 4 threads per node.
// Gather each thread's float4 slice; exchange a/g via width-4 shuffles;
// each thread computes j in [p*8, p*8+8) of h1 = relu(a@Wr + g@Wl + b).
__global__ __launch_bounds__(256) void k_g1f(
    const float* __restrict__ x, const int* __restrict__ rs,
    const int* __restrict__ esrc,
    const float* __restrict__ wroot, const float* __restrict__ wrel,
    const float* __restrict__ bias, float* __restrict__ h1, int N)
{
    __shared__ float4 s_wr[128], s_wl[128], s_b[8];   // 16x32 each, bias 32
    int t = threadIdx.x;
    if (t < 128) {
        s_wr[t] = reinterpret_cast<const float4*>(wroot)[t];
        s_wl[t] = reinterpret_cast<const float4*>(wrel)[t];
    }
    if (t < 8) s_b[t] = reinterpret_cast<const float4*>(bias)[t];
    __syncthreads();

    int tid = blockIdx.x * 256 + t;
    int n = tid >> 2, p = tid & 3;
    if (n >= N) return;
    int s0 = rs[n], s1 = rs[n + 1];
    float4 g = make_float4(0.f, 0.f, 0.f, 0.f);
    int e = s0;
    for (; e + 1 < s1; e += 2) {
        int src0 = esrc[e], src1 = esrc[e + 1];
        float4 v0 = *reinterpret_cast<const float4*>(x + (size_t)src0 * 16 + p * 4);
        float4 v1 = *reinterpret_cast<const float4*>(x + (size_t)src1 * 16 + p * 4);
        g.x += v0.x + v1.x; g.y += v0.y + v1.y;
        g.z += v0.z + v1.z; g.w += v0.w + v1.w;
    }
    if (e < s1) {
        int src0 = esrc[e];
        float4 v0 = *reinterpret_cast<const float4*>(x + (size_t)src0 * 16 + p * 4);
        g.x += v0.x; g.y += v0.y; g.z += v0.z; g.w += v0.w;
    }
    float4 a = *reinterpret_cast<const float4*>(x + (size_t)n * 16 + p * 4);

    int jb = p * 2;                          // my 2 float4 columns of 8
    float4 acc0 = s_b[jb], acc1 = s_b[jb + 1];
#pragma unroll
    for (int kc = 0; kc < 4; ++kc) {
        float4 a4 = shfl4b(a, kc);
        float4 g4 = shfl4b(g, kc);
#pragma unroll
        for (int kk = 0; kk < 4; ++kk) {
            float av = F4E(a4, kk), gv = F4E(g4, kk);
            int k = kc * 4 + kk;
            float4 wr0 = s_wr[k * 8 + jb], wr1 = s_wr[k * 8 + jb + 1];
            float4 wl0 = s_wl[k * 8 + jb], wl1 = s_wl[k * 8 + jb + 1];
            acc0.x += av * wr0.x + gv * wl0.x;
            acc0.y += av * wr0.y + gv * wl0.y;
            acc0.z += av * wr0.z + gv * wl0.z;
            acc0.w += av * wr0.w + gv * wl0.w;
            acc1.x += av * wr1.x + gv * wl1.x;
            acc1.y += av * wr1.y + gv * wl1.y;
            acc1.z += av * wr1.z + gv * wl1.z;
            acc1.w += av * wr1.w + gv * wl1.w;
        }
    }
    acc0.x = fmaxf(acc0.x, 0.f); acc0.y = fmaxf(acc0.y, 0.f);
    acc0.z = fmaxf(acc0.z, 0.f); acc0.w = fmaxf(acc0.w, 0.f);
    acc1.x = fmaxf(acc1.x, 0.f); acc1.y = fmaxf(acc1.y, 0.f);
    acc1.z = fmaxf(acc1.z, 0.f); acc1.w = fmaxf(acc1.w, 0.f);
    float4* o = reinterpret_cast<float4*>(h1 + (size_t)n * 32 + p * 8);
    o[0] = acc0; o[1] = acc1;
}

// ---------------------------------------------------------------------------
// Gather-sum, F=32: 8 threads per node (unchanged; proven fast).
__global__ __launch_bounds__(256) void k_gather32(
    const float* __restrict__ x, const int* __restrict__ rs,
    const int* __restrict__ esrc, float* __restrict__ agg, int N)
{
    int tid = blockIdx.x * 256 + threadIdx.x;
    int n = tid >> 3, p = tid & 7;
    if (n >= N) return;
    int s0 = rs[n], s1 = rs[n + 1];
    float4 acc = make_float4(0.f, 0.f, 0.f, 0.f);
    int e = s0;
    for (; e + 1 < s1; e += 2) {
        int src0 = esrc[e], src1 = esrc[e + 1];
        float4 v0 = *reinterpret_cast<const float4*>(x + (size_t)src0 * 32 + p * 4);
        float4 v1 = *reinterpret_cast<const float4*>(x + (size_t)src1 * 32 + p * 4);
        acc.x += v0.x + v1.x; acc.y += v0.y + v1.y;
        acc.z += v0.z + v1.z; acc.w += v0.w + v1.w;
    }
    if (e < s1) {
        int src0 = esrc[e];
        float4 v0 = *reinterpret_cast<const float4*>(x + (size_t)src0 * 32 + p * 4);
        acc.x += v0.x; acc.y += v0.y; acc.z += v0.z; acc.w += v0.w;
    }
    *reinterpret_cast<float4*>(agg + (size_t)n * 32 + p * 4) = acc;
}

// ---------------------------------------------------------------------------
// Fused layer2 + fc1 + fc2, 2 threads per node (j-split).
// Thread p computes h2[j in p*32..p*32+32), fc1 via k-split partials +
// pair shfl_xor reduce, fc2 j-split. Writes final output.
__global__ __launch_bounds__(256) void k_l2v2(
    const float* __restrict__ h1, const float* __restrict__ agg,
    const float* __restrict__ wroot, const float* __restrict__ wrel,
    const float* __restrict__ bias,
    const float* __restrict__ f1w, const float* __restrict__ f1b,
    const float* __restrict__ f2w, const float* __restrict__ f2b,
    float* __restrict__ out, int N)
{
    __shared__ float4 s_wr[512], s_wl[512], s_b[16];  // 32x64 weights, bias 64
    __shared__ float4 s_f1[512], s_f2[128], s_b1[8], s_b2[4];
    int t = threadIdx.x;
    for (int i = t; i < 512; i += 256) {
        s_wr[i] = reinterpret_cast<const float4*>(wroot)[i];
        s_wl[i] = reinterpret_cast<const float4*>(wrel)[i];
        s_f1[i] = reinterpret_cast<const float4*>(f1w)[i];
    }
    if (t < 128) s_f2[t] = reinterpret_cast<const float4*>(f2w)[t];
    if (t < 16) s_b[t]  = reinterpret_cast<const float4*>(bias)[t];
    if (t < 8)  s_b1[t] = reinterpret_cast<const float4*>(f1b)[t];
    if (t < 4)  s_b2[t] = reinterpret_cast<const float4*>(f2b)[t];
    __syncthreads();

    int gid = blockIdx.x * 256 + t;
    int n = gid >> 1, p = gid & 1;
    if (n >= N) return;
    const float4* xr = reinterpret_cast<const float4*>(h1 + (size_t)n * 32);
    const float4* ar = reinterpret_cast<const float4*>(agg + (size_t)n * 32);
    float4 X0 = xr[0], X1 = xr[1], X2 = xr[2], X3 = xr[3];
    float4 X4 = xr[4], X5 = xr[5], X6 = xr[6], X7 = xr[7];
    float4 G0 = ar[0], G1 = ar[1], G2 = ar[2], G3 = ar[3];
    float4 G4 = ar[4], G5 = ar[5], G6 = ar[6], G7 = ar[7];

    // layer2: my 32 of 64 h2 outputs (8 float4), j-base = p*32.
    int jb = p * 8;                              // float4-column base
    float4 acc[8];
#pragma unroll
    for (int jc = 0; jc < 8; ++jc) acc[jc] = s_b[jb + jc];

#define L2STEP(Xc, Gc, kcv)                                          \
    {                                                                \
        _Pragma("unroll")                                            \
        for (int kk = 0; kk < 4; ++kk) {                             \
            float a = F4E(Xc, kk), g = F4E(Gc, kk);                  \
            int k = (kcv) * 4 + kk;                                  \
            _Pragma("unroll")                                        \
            for (int jc = 0; jc < 8; ++jc) {                         \
                float4 wr = s_wr[k * 16 + jb + jc];                  \
                float4 wl = s_wl[k * 16 + jb + jc];                  \
                acc[jc].x += a * wr.x + g * wl.x;                    \
                acc[jc].y += a * wr.y + g * wl.y;                    \
                acc[jc].z += a * wr.z + g * wl.z;                    \
                acc[jc].w += a * wr.w + g * wl.w;                    \
            }                                                        \
        }                                                            \
    }
    L2STEP(X0, G0, 0) L2STEP(X1, G1, 1) L2STEP(X2, G2, 2) L2STEP(X3, G3, 3)
    L2STEP(X4, G4, 4) L2STEP(X5, G5, 5) L2STEP(X6, G6, 6) L2STEP(X7, G7, 7)
#undef L2STEP

#pragma unroll
    for (int jc = 0; jc < 8; ++jc) {
        acc[jc].x = fmaxf(acc[jc].x, 0.f); acc[jc].y = fmaxf(acc[jc].y, 0.f);
        acc[jc].z = fmaxf(acc[jc].z, 0.f); acc[jc].w = fmaxf(acc[jc].w, 0.f);
    }

    // fc1 k-split: my 32 h2 values (k = p*32+kk) x all 32 outputs.
    float4 f[8];
    float4 z4 = make_float4(0.f, 0.f, 0.f, 0.f);
#pragma unroll
    for (int jc = 0; jc < 8; ++jc) f[jc] = p ? z4 : s_b1[jc];
#pragma unroll
    for (int kk = 0; kk < 32; ++kk) {
        float hv = F4E(acc[kk >> 2], kk & 3);
        int k = p * 32 + kk;
#pragma unroll
        for (int jc = 0; jc < 8; ++jc) {
            float4 w = s_f1[k * 8 + jc];
            f[jc].x += hv * w.x; f[jc].y += hv * w.y;
            f[jc].z += hv * w.z; f[jc].w += hv * w.w;
        }
    }
    // pair reduce (both lanes end with the full fc1 output) + relu
#pragma unroll
    for (int jc = 0; jc < 8; ++jc) {
        f[jc].x += __shfl_xor(f[jc].x, 1);
        f[jc].y += __shfl_xor(f[jc].y, 1);
        f[jc].z += __shfl_xor(f[jc].z, 1);
        f[jc].w += __shfl_xor(f[jc].w, 1);
        f[jc].x = fmaxf(f[jc].x, 0.f); f[jc].y = fmaxf(f[jc].y, 0.f);
        f[jc].z = fmaxf(f[jc].z, 0.f); f[jc].w = fmaxf(f[jc].w, 0.f);
    }

    // fc2 j-split: my 8 of 16 outputs.
    int ob = p * 2;
    float4 o0 = s_b2[ob], o1 = s_b2[ob + 1];
#pragma unroll
    for (int k2 = 0; k2 < 32; ++k2) {
        float a = F4E(f[k2 >> 2], k2 & 3);
        float4 w0 = s_f2[k2 * 4 + ob], w1 = s_f2[k2 * 4 + ob + 1];
        o0.x += a * w0.x; o0.y += a * w0.y; o0.z += a * w0.z; o0.w += a * w0.w;
        o1.x += a * w1.x; o1.y += a * w1.y; o1.z += a * w1.z; o1.w += a * w1.w;
    }
    float4* o = reinterpret_cast<float4*>(out + (size_t)n * 16 + p * 8);
    o[0] = o0; o[1] = o1;
}

// ---------------------------------------------------------------------------
extern "C" void kernel_launch(void* const* d_in, const int* in_sizes, int n_in,
                              void* d_out, int out_size, void* d_ws, size_t ws_size,
                              hipStream_t stream)
{
    const float* x   = (const float*)d_in[0];
    const int*   ei  = (const int*)d_in[1];
    const float* wr1 = (const float*)d_in[2];
    const float* wl1 = (const float*)d_in[3];
    const float* b1  = (const float*)d_in[4];
    const float* wr2 = (const float*)d_in[5];
    const float* wl2 = (const float*)d_in[6];
    const float* b2  = (const float*)d_in[7];
    const float* f1w = (const float*)d_in[8];
    const float* f1b = (const float*)d_in[9];
    const float* f2w = (const float*)d_in[10];
    const float* f2b = (const float*)d_in[11];
    float* out = (float*)d_out;

    const int N  = in_sizes[0] / 16;
    const int E  = in_sizes[1] / 2;
    const int NB = (N + 255) >> 8;      // 256 nodes per bucket, NB <= 512

    // Workspace layout (floats/ints, no aliasing; ~38.8MB of >=51.2MB):
    //   h1      : N*32 floats   12.8 MB
    //   agg2    : N*32 floats   12.8 MB
    //   esorted : E ints         6.4 MB
    //   epack   : E ints         6.4 MB
    //   rs      : N+1 ints; bhist/bstart/gcursor tiny
    float* ws      = (float*)d_ws;
    float* h1      = ws;
    float* agg2    = ws + (size_t)N * 32;
    int*   esorted = (int*)(ws + (size_t)N * 64);
    int*   epack   = esorted + E;
    int*   rs      = epack + E;
    int*   bhist   = rs + N + 1;
    int*   bstart  = bhist + NB;
    int*   gcursor = bstart + NB + 1;

    hipMemsetAsync(bhist, 0, (size_t)NB * sizeof(int), stream);

    int nchunk = (E + CHUNK - 1) / CHUNK;
    int g_g1 = (N * 4 + 255) / 256;
    int g_g2 = (N * 8 + 255) / 256;
    int g_l2 = (N * 2 + 255) / 256;

    k_bhist    <<<nchunk, 512, 0, stream>>>(ei, bhist, E, NB);
    k_bscan    <<<1,      512, 0, stream>>>(bhist, bstart, gcursor, NB, E);
    k_partition<<<nchunk, 512, 0, stream>>>(ei, gcursor, epack, E);
    k_sort     <<<NB,     256, 0, stream>>>(bstart, epack, rs, esorted, N, E);

    k_g1f      <<<g_g1, 256, 0, stream>>>(x, rs, esorted, wr1, wl1, b1, h1, N);
    k_gather32 <<<g_g2, 256, 0, stream>>>(h1, rs, esorted, agg2, N);
    k_l2v2     <<<g_l2, 256, 0, stream>>>(h1, agg2, wr2, wl2, b2,
                                          f1w, f1b, f2w, f2b, out, N);
}

// Round 7
// 229.477 us; speedup vs baseline: 3.0139x; 1.0117x over previous
//
#include <hip/hip_runtime.h>

// Static float4 component access (folds to .x/.y/.z/.w after unroll).
#define F4E(v,i) ((i)==0?(v).x:((i)==1?(v).y:((i)==2?(v).z:(v).w)))

#define CHUNK 4096      // edges per partition block (512 threads x 8)
#define ITERS 8

__device__ inline float4 shfl4b(float4 v, int src) {
    float4 r;
    r.x = __shfl(v.x, src, 4); r.y = __shfl(v.y, src, 4);
    r.z = __shfl(v.z, src, 4); r.w = __shfl(v.w, src, 4);
    return r;
}
__device__ inline float4 shfl8b(float4 v, int src) {
    float4 r;
    r.x = __shfl(v.x, src, 8); r.y = __shfl(v.y, src, 8);
    r.z = __shfl(v.z, src, 8); r.w = __shfl(v.w, src, 8);
    return r;
}

// ---------------------------------------------------------------------------
// Bucket histogram: bucket = dst >> 8 (256 nodes per bucket), NB <= 512.
__global__ __launch_bounds__(512) void k_bhist(
    const int* __restrict__ ei, int* __restrict__ bhist, int E, int NB)
{
    __shared__ int cnt[512];
    int t = threadIdx.x;
    cnt[t] = 0;
    __syncthreads();
    int base = blockIdx.x * CHUNK;
#pragma unroll
    for (int i = 0; i < ITERS; ++i) {
        int e = base + i * 512 + t;
        if (e < E) {
            int dst = ei[E + e];
            atomicAdd(&cnt[dst >> 8], 1);
        }
    }
    __syncthreads();
    if (t < NB && cnt[t]) atomicAdd(&bhist[t], cnt[t]);
}

// Exclusive scan of bucket counts (NB <= 512), writes bstart + cursor init.
__global__ __launch_bounds__(512) void k_bscan(
    const int* __restrict__ bhist, int* __restrict__ bstart,
    int* __restrict__ gcursor, int NB, int E)
{
    __shared__ int s[512];
    int t = threadIdx.x;
    int v0 = (t < NB) ? bhist[t] : 0;
    s[t] = v0;
    __syncthreads();
    for (int off = 1; off < 512; off <<= 1) {
        int v = (t >= off) ? s[t - off] : 0;
        __syncthreads();
        s[t] += v;
        __syncthreads();
    }
    if (t < NB) { int ex = s[t] - v0; bstart[t] = ex; gcursor[t] = ex; }
    if (t == 0) bstart[NB] = E;
}

// Partition edges into bucket-contiguous packed list, coalesced flush.
// packed = (src << 8) | (dst & 255); requires N < 2^17 (holds: 100000).
__global__ __launch_bounds__(512) void k_partition(
    const int* __restrict__ ei, int* __restrict__ gcursor,
    int* __restrict__ epack, int E)
{
    __shared__ int cnt[512], sc[512], lbase[512], gbase[512], lcnt[512];
    __shared__ int stage[CHUNK];
    __shared__ unsigned short stageb[CHUNK];
    int t = threadIdx.x;
    cnt[t] = 0; lcnt[t] = 0;
    __syncthreads();

    int base = blockIdx.x * CHUNK;
    int pk[ITERS], bb[ITERS];
#pragma unroll
    for (int i = 0; i < ITERS; ++i) {
        int e = base + i * 512 + t;
        if (e < E) {
            int src = ei[e], dst = ei[E + e];
            pk[i] = (src << 8) | (dst & 255);
            bb[i] = dst >> 8;
            atomicAdd(&cnt[bb[i]], 1);
        } else bb[i] = -1;
    }
    __syncthreads();

    int v0 = cnt[t];
    sc[t] = v0;
    __syncthreads();
    for (int off = 1; off < 512; off <<= 1) {
        int v = (t >= off) ? sc[t - off] : 0;
        __syncthreads();
        sc[t] += v;
        __syncthreads();
    }
    lbase[t] = sc[t] - v0;
    if (v0 > 0) gbase[t] = atomicAdd(&gcursor[t], v0);
    __syncthreads();

#pragma unroll
    for (int i = 0; i < ITERS; ++i) {
        if (bb[i] >= 0) {
            int loc = atomicAdd(&lcnt[bb[i]], 1);
            int slot = lbase[bb[i]] + loc;
            stage[slot] = pk[i];
            stageb[slot] = (unsigned short)bb[i];
        }
    }
    __syncthreads();

    int m = min(CHUNK, E - base);
#pragma unroll
    for (int i = 0; i < ITERS; ++i) {
        int slot = i * 512 + t;
        if (slot < m) {
            int b = stageb[slot];
            epack[gbase[b] + (slot - lbase[b])] = stage[slot];
        }
    }
}

// ---------------------------------------------------------------------------
// Per-bucket counting sort by dst&255 -> per-node CSR (rs + esorted of src).
__global__ __launch_bounds__(256) void k_sort(
    const int* __restrict__ bstart, const int* __restrict__ epack,
    int* __restrict__ rs, int* __restrict__ esorted, int N, int E)
{
    __shared__ int hist[256], cur[256], sc[256];
    int t = threadIdx.x;
    int b = blockIdx.x;
    int s0 = bstart[b], s1 = bstart[b + 1];
    hist[t] = 0;
    __syncthreads();
    for (int e = s0 + t; e < s1; e += 256)
        atomicAdd(&hist[epack[e] & 255], 1);
    __syncthreads();

    int v0 = hist[t];
    sc[t] = v0;
    __syncthreads();
    for (int off = 1; off < 256; off <<= 1) {
        int v = (t >= off) ? sc[t - off] : 0;
        __syncthreads();
        sc[t] += v;
        __syncthreads();
    }
    int excl = sc[t] - v0;
    cur[t] = excl;
    int node = (b << 8) + t;
    if (node < N) rs[node] = s0 + excl;
    if (b == 0 && t == 0) rs[N] = E;
    __syncthreads();

    for (int e = s0 + t; e < s1; e += 256) {
        int pk = epack[e];
        int dlo = pk & 255;
        int pos = s0 + atomicAdd(&cur[dlo], 1);
        esorted[pos] = ((unsigned)pk) >> 8;
    }
}

// ---------------------------------------------------------------------------
// Fused gather(F=16) + layer1: 4 threads per node.
__global__ __launch_bounds__(256) void k_g1f(
    const float* __restrict__ x, const int* __restrict__ rs,
    const int* __restrict__ esrc,
    const float* __restrict__ wroot, const float* __restrict__ wrel,
    const float* __restrict__ bias, float* __restrict__ h1, int N)
{
    __shared__ float4 s_wr[128], s_wl[128], s_b[8];   // 16x32 each, bias 32
    int t = threadIdx.x;
    if (t < 128) {
        s_wr[t] = reinterpret_cast<const float4*>(wroot)[t];
        s_wl[t] = reinterpret_cast<const float4*>(wrel)[t];
    }
    if (t < 8) s_b[t] = reinterpret_cast<const float4*>(bias)[t];
    __syncthreads();

    int tid = blockIdx.x * 256 + t;
    int n = tid >> 2, p = tid & 3;
    if (n >= N) return;
    int s0 = rs[n], s1 = rs[n + 1];
    float4 g = make_float4(0.f, 0.f, 0.f, 0.f);
    int e = s0;
    for (; e + 1 < s1; e += 2) {
        int src0 = esrc[e], src1 = esrc[e + 1];
        float4 v0 = *reinterpret_cast<const float4*>(x + (size_t)src0 * 16 + p * 4);
        float4 v1 = *reinterpret_cast<const float4*>(x + (size_t)src1 * 16 + p * 4);
        g.x += v0.x + v1.x; g.y += v0.y + v1.y;
        g.z += v0.z + v1.z; g.w += v0.w + v1.w;
    }
    if (e < s1) {
        int src0 = esrc[e];
        float4 v0 = *reinterpret_cast<const float4*>(x + (size_t)src0 * 16 + p * 4);
        g.x += v0.x; g.y += v0.y; g.z += v0.z; g.w += v0.w;
    }
    float4 a = *reinterpret_cast<const float4*>(x + (size_t)n * 16 + p * 4);

    int jb = p * 2;                          // my 2 float4 columns of 8
    float4 acc0 = s_b[jb], acc1 = s_b[jb + 1];
#pragma unroll
    for (int kc = 0; kc < 4; ++kc) {
        float4 a4 = shfl4b(a, kc);
        float4 g4 = shfl4b(g, kc);
#pragma unroll
        for (int kk = 0; kk < 4; ++kk) {
            float av = F4E(a4, kk), gv = F4E(g4, kk);
            int k = kc * 4 + kk;
            float4 wr0 = s_wr[k * 8 + jb], wr1 = s_wr[k * 8 + jb + 1];
            float4 wl0 = s_wl[k * 8 + jb], wl1 = s_wl[k * 8 + jb + 1];
            acc0.x += av * wr0.x + gv * wl0.x;
            acc0.y += av * wr0.y + gv * wl0.y;
            acc0.z += av * wr0.z + gv * wl0.z;
            acc0.w += av * wr0.w + gv * wl0.w;
            acc1.x += av * wr1.x + gv * wl1.x;
            acc1.y += av * wr1.y + gv * wl1.y;
            acc1.z += av * wr1.z + gv * wl1.z;
            acc1.w += av * wr1.w + gv * wl1.w;
        }
    }
    acc0.x = fmaxf(acc0.x, 0.f); acc0.y = fmaxf(acc0.y, 0.f);
    acc0.z = fmaxf(acc0.z, 0.f); acc0.w = fmaxf(acc0.w, 0.f);
    acc1.x = fmaxf(acc1.x, 0.f); acc1.y = fmaxf(acc1.y, 0.f);
    acc1.z = fmaxf(acc1.z, 0.f); acc1.w = fmaxf(acc1.w, 0.f);
    float4* o = reinterpret_cast<float4*>(h1 + (size_t)n * 32 + p * 8);
    o[0] = acc0; o[1] = acc1;
}

// ---------------------------------------------------------------------------
// Fused gather(F=32) + layer2 + fc1 + fc2: 8 threads per node.
// Gather agg slice in registers; width-8 shuffles broadcast a/g rows;
// layer2 j-split (8 outs/thread), fc1 k-split + butterfly reduce,
// fc2 j-split (2 outs/thread). Writes final output directly.
__global__ __launch_bounds__(256) void k_g2f(
    const float* __restrict__ h1, const int* __restrict__ rs,
    const int* __restrict__ esrc,
    const float* __restrict__ wroot, const float* __restrict__ wrel,
    const float* __restrict__ bias,
    const float* __restrict__ f1w, const float* __restrict__ f1b,
    const float* __restrict__ f2w, const float* __restrict__ f2b,
    float* __restrict__ out, int N)
{
    __shared__ float4 s_wr[512], s_wl[512], s_b[16];  // 32x64 weights, bias 64
    __shared__ float4 s_f1[512];                      // 64x32, jc-swizzled
    __shared__ float  s_f2[512];                      // 32x16
    __shared__ float4 s_b1[8];
    __shared__ float  s_b2[16];
    int t = threadIdx.x;
    for (int i = t; i < 512; i += 256) {
        s_wr[i] = reinterpret_cast<const float4*>(wroot)[i];
        s_wl[i] = reinterpret_cast<const float4*>(wrel)[i];
        // swizzle: row k (= i>>3), col jc (= i&7) stored at jc' = (jc + (k>>3)) & 7
        // so the 8 k-split lanes (k = p*8+kk, k>>3 == p) hit 8 distinct banks.
        int k = i >> 3, jc = i & 7;
        s_f1[(i & ~7) | ((jc + (k >> 3)) & 7)] = reinterpret_cast<const float4*>(f1w)[i];
        s_f2[i] = f2w[i];
    }
    if (t < 16) s_b[t]  = reinterpret_cast<const float4*>(bias)[t];
    if (t < 8)  s_b1[t] = reinterpret_cast<const float4*>(f1b)[t];
    if (t < 16) s_b2[t] = f2b[t];
    __syncthreads();

    int tid = blockIdx.x * 256 + t;
    int n = tid >> 3, p = tid & 7;
    if (n >= N) return;

    // gather my float4 slice of agg2
    int s0 = rs[n], s1 = rs[n + 1];
    float4 g = make_float4(0.f, 0.f, 0.f, 0.f);
    int e = s0;
    for (; e + 1 < s1; e += 2) {
        int src0 = esrc[e], src1 = esrc[e + 1];
        float4 v0 = *reinterpret_cast<const float4*>(h1 + (size_t)src0 * 32 + p * 4);
        float4 v1 = *reinterpret_cast<const float4*>(h1 + (size_t)src1 * 32 + p * 4);
        g.x += v0.x + v1.x; g.y += v0.y + v1.y;
        g.z += v0.z + v1.z; g.w += v0.w + v1.w;
    }
    if (e < s1) {
        int src0 = esrc[e];
        float4 v0 = *reinterpret_cast<const float4*>(h1 + (size_t)src0 * 32 + p * 4);
        g.x += v0.x; g.y += v0.y; g.z += v0.z; g.w += v0.w;
    }
    float4 a = *reinterpret_cast<const float4*>(h1 + (size_t)n * 32 + p * 4);

    // layer2: my 8 of 64 h2 outputs (j in [p*8, p*8+8)), jb = p*2 float4 cols
    int jb = p * 2;
    float4 acc0 = s_b[jb], acc1 = s_b[jb + 1];
#pragma unroll
    for (int kc = 0; kc < 8; ++kc) {
        float4 a4 = shfl8b(a, kc);
        float4 g4 = shfl8b(g, kc);
#pragma unroll
        for (int kk = 0; kk < 4; ++kk) {
            float av = F4E(a4, kk), gv = F4E(g4, kk);
            int k = kc * 4 + kk;
            float4 wr0 = s_wr[k * 16 + jb], wr1 = s_wr[k * 16 + jb + 1];
            float4 wl0 = s_wl[k * 16 + jb], wl1 = s_wl[k * 16 + jb + 1];
            acc0.x += av * wr0.x + gv * wl0.x;
            acc0.y += av * wr0.y + gv * wl0.y;
            acc0.z += av * wr0.z + gv * wl0.z;
            acc0.w += av * wr0.w + gv * wl0.w;
            acc1.x += av * wr1.x + gv * wl1.x;
            acc1.y += av * wr1.y + gv * wl1.y;
            acc1.z += av * wr1.z + gv * wl1.z;
            acc1.w += av * wr1.w + gv * wl1.w;
        }
    }
    acc0.x = fmaxf(acc0.x, 0.f); acc0.y = fmaxf(acc0.y, 0.f);
    acc0.z = fmaxf(acc0.z, 0.f); acc0.w = fmaxf(acc0.w, 0.f);
    acc1.x = fmaxf(acc1.x, 0.f); acc1.y = fmaxf(acc1.y, 0.f);
    acc1.z = fmaxf(acc1.z, 0.f); acc1.w = fmaxf(acc1.w, 0.f);

    // fc1 k-split: my 8 h2 values are k = p*8 + kk; partials over all 32 outs.
    // Read at swizzled slot ((jc+p)&7) -> retrieves ORIGINAL column jc
    // (store swizzle was +p for these rows); accumulate into f[jc] so all
    // lanes' partials line up for the butterfly reduce. (Round-6 bug was
    // accumulating into f[(jc+p)&7].)
    float4 f[8];
    float4 z4 = make_float4(0.f, 0.f, 0.f, 0.f);
#pragma unroll
    for (int jc = 0; jc < 8; ++jc) f[jc] = p ? z4 : s_b1[jc];
#pragma unroll
    for (int kk = 0; kk < 8; ++kk) {
        float hv = (kk < 4) ? F4E(acc0, kk) : F4E(acc1, kk - 4);
        int k = p * 8 + kk;
        int row = k * 8;
#pragma unroll
        for (int jc = 0; jc < 8; ++jc) {
            float4 w = s_f1[row | ((jc + p) & 7)];
            f[jc].x += hv * w.x; f[jc].y += hv * w.y;
            f[jc].z += hv * w.z; f[jc].w += hv * w.w;
        }
    }
    // butterfly reduce across the 8-lane group + relu
#pragma unroll
    for (int m = 1; m < 8; m <<= 1) {
#pragma unroll
        for (int jc = 0; jc < 8; ++jc) {
            f[jc].x += __shfl_xor(f[jc].x, m);
            f[jc].y += __shfl_xor(f[jc].y, m);
            f[jc].z += __shfl_xor(f[jc].z, m);
            f[jc].w += __shfl_xor(f[jc].w, m);
        }
    }
#pragma unroll
    for (int jc = 0; jc < 8; ++jc) {
        f[jc].x = fmaxf(f[jc].x, 0.f); f[jc].y = fmaxf(f[jc].y, 0.f);
        f[jc].z = fmaxf(f[jc].z, 0.f); f[jc].w = fmaxf(f[jc].w, 0.f);
    }

    // fc2 j-split: my 2 of 16 outputs (j = p*2, p*2+1).
    float o0 = s_b2[p * 2], o1 = s_b2[p * 2 + 1];
#pragma unroll
    for (int k2 = 0; k2 < 32; ++k2) {
        float av = F4E(f[k2 >> 2], k2 & 3);
        o0 += av * s_f2[k2 * 16 + p * 2];
        o1 += av * s_f2[k2 * 16 + p * 2 + 1];
    }
    float2* o = reinterpret_cast<float2*>(out + (size_t)n * 16 + p * 2);
    *o = make_float2(o0, o1);
}

// ---------------------------------------------------------------------------
extern "C" void kernel_launch(void* const* d_in, const int* in_sizes, int n_in,
                              void* d_out, int out_size, void* d_ws, size_t ws_size,
                              hipStream_t stream)
{
    const float* x   = (const float*)d_in[0];
    const int*   ei  = (const int*)d_in[1];
    const float* wr1 = (const float*)d_in[2];
    const float* wl1 = (const float*)d_in[3];
    const float* b1  = (const float*)d_in[4];
    const float* wr2 = (const float*)d_in[5];
    const float* wl2 = (const float*)d_in[6];
    const float* b2  = (const float*)d_in[7];
    const float* f1w = (const float*)d_in[8];
    const float* f1b = (const float*)d_in[9];
    const float* f2w = (const float*)d_in[10];
    const float* f2b = (const float*)d_in[11];
    float* out = (float*)d_out;

    const int N  = in_sizes[0] / 16;
    const int E  = in_sizes[1] / 2;
    const int NB = (N + 255) >> 8;      // 256 nodes per bucket, NB <= 512

    // Workspace layout (floats/ints, no aliasing; ~26MB of >=51.2MB):
    //   h1      : N*32 floats   12.8 MB
    //   esorted : E ints         6.4 MB
    //   epack   : E ints         6.4 MB
    //   rs      : N+1 ints; bhist/bstart/gcursor tiny
    float* ws      = (float*)d_ws;
    float* h1      = ws;
    int*   esorted = (int*)(ws + (size_t)N * 32);
    int*   epack   = esorted + E;
    int*   rs      = epack + E;
    int*   bhist   = rs + N + 1;
    int*   bstart  = bhist + NB;
    int*   gcursor = bstart + NB + 1;

    hipMemsetAsync(bhist, 0, (size_t)NB * sizeof(int), stream);

    int nchunk = (E + CHUNK - 1) / CHUNK;
    int g_g1 = (N * 4 + 255) / 256;
    int g_g2 = (N * 8 + 255) / 256;

    k_bhist    <<<nchunk, 512, 0, stream>>>(ei, bhist, E, NB);
    k_bscan    <<<1,      512, 0, stream>>>(bhist, bstart, gcursor, NB, E);
    k_partition<<<nchunk, 512, 0, stream>>>(ei, gcursor, epack, E);
    k_sort     <<<NB,     256, 0, stream>>>(bstart, epack, rs, esorted, N, E);

    k_g1f      <<<g_g1, 256, 0, stream>>>(x, rs, esorted, wr1, wl1, b1, h1, N);
    k_g2f      <<<g_g2, 256, 0, stream>>>(h1, rs, esorted, wr2, wl2, b2,
                                          f1w, f1b, f2w, f2b, out, N);
}